// Round 7
// baseline (3173.197 us; speedup 1.0000x reference)
//
#include <hip/hip_runtime.h>
#include <cstdint>

#define NB 16384   // batch
#define NM 256     // M
#define NN 1024    // N
#define NITER 16
#define TOPK 50
#define BMROW 16               // batch rows per gemm2_update block
#define NBLKS2 (NB / BMROW)    // 1024 blocks

typedef __attribute__((ext_vector_type(8))) short short8;   // 8 bf16 = 4 VGPRs
typedef __attribute__((ext_vector_type(4))) float f32x4;

__device__ inline unsigned short f2bf(float x) {            // RNE fp32 -> bf16
    unsigned u = __float_as_uint(x);
    return (unsigned short)((u + 0x7FFFu + ((u >> 16) & 1u)) >> 16);
}
__device__ inline float bf2f(unsigned short h) {
    return __uint_as_float(((unsigned)h) << 16);
}
__device__ inline void gload16(const void* g, void* lds_) {  // 16B global -> LDS
    __builtin_amdgcn_global_load_lds(
        (const __attribute__((address_space(1))) unsigned*)g,
        (__attribute__((address_space(3))) unsigned*)lds_, 16, 0, 0);
}

// ------------- precompute: element-wise split of phi (NM x NN) -------------
__global__ __launch_bounds__(256) void split_phi_kernel(const float* __restrict__ phi,
                                                        unsigned short* __restrict__ h,
                                                        unsigned short* __restrict__ l) {
    int i = blockIdx.x * 256 + threadIdx.x;
    float v = phi[i];
    unsigned short hh = f2bf(v);
    h[i] = hh;
    l[i] = f2bf(v - bf2f(hh));
}

// -------- precompute: W (NM x NN) -> Wt (NN x NM) transposed + split -------
__global__ __launch_bounds__(256) void transpose_split_W(const float* __restrict__ W,
                                                         unsigned short* __restrict__ th,
                                                         unsigned short* __restrict__ tl) {
    __shared__ float tile[32][33];
    int n0 = blockIdx.x * 32;
    int m0 = blockIdx.y * 32;
    int tx = threadIdx.x;   // 0..31
    int ty = threadIdx.y;   // 0..7
    #pragma unroll
    for (int i = 0; i < 32; i += 8)
        tile[ty + i][tx] = W[(size_t)(m0 + ty + i) * NN + n0 + tx];
    __syncthreads();
    #pragma unroll
    for (int i = 0; i < 32; i += 8) {
        float v = tile[tx][ty + i];
        unsigned short hh = f2bf(v);
        size_t idx = (size_t)(n0 + ty + i) * NM + m0 + tx;
        th[idx] = hh;
        tl[idx] = f2bf(v - bf2f(hh));
    }
}

// ---- GEMM1 (round-0 verbatim, proven): Rt(B x NM) = X(B x NN) @ phiT - y ----
#define BM1 128
#define BN1 64
#define BK  32
__global__ __launch_bounds__(256) void gemm1_mfma(const unsigned short* __restrict__ Xh,
                                                  const unsigned short* __restrict__ Xl,
                                                  const unsigned short* __restrict__ Ph,
                                                  const unsigned short* __restrict__ Pl,
                                                  const float* __restrict__ y,
                                                  unsigned short* __restrict__ Rth,
                                                  unsigned short* __restrict__ Rtl) {
    __shared__ unsigned short sAh[BM1 * BK];  // 8KB, row stride 32 elem = 64B
    __shared__ unsigned short sAl[BM1 * BK];
    __shared__ unsigned short sBh[BN1 * BK];  // 4KB
    __shared__ unsigned short sBl[BN1 * BK];

    const int tid = threadIdx.x, wave = tid >> 6, lane = tid & 63;
    const int b0 = blockIdx.x * BM1, n0 = blockIdx.y * BN1;
    const int wm = (wave & 1) * 64, wn = (wave >> 1) * 32;
    const int row16 = lane & 15, quad = lane >> 4;

    f32x4 acc[4][2];
    #pragma unroll
    for (int i = 0; i < 4; i++)
        #pragma unroll
        for (int j = 0; j < 2; j++) acc[i][j] = (f32x4){0.f, 0.f, 0.f, 0.f};

    for (int k0 = 0; k0 < NN; k0 += BK) {
        #pragma unroll
        for (int c = 0; c < 2; ++c) {          // A tiles: 8 chunks of 1KB
            int o = (wave * 2 + c) * 1024 + lane * 16;   // byte offset in tile
            int row = o >> 6, colb = o & 63;
            size_t g = (size_t)(b0 + row) * NN + k0 + (colb >> 1);
            gload16(&Xh[g], (char*)sAh + o);
            gload16(&Xl[g], (char*)sAl + o);
        }
        {                                       // B tiles: 4 chunks of 1KB
            int o = wave * 1024 + lane * 16;
            int nrow = o >> 6, colb = o & 63;
            size_t g = (size_t)(n0 + nrow) * NN + k0 + (colb >> 1);
            gload16(&Ph[g], (char*)sBh + o);
            gload16(&Pl[g], (char*)sBl + o);
        }
        __syncthreads();
        short8 a[4], bh[2], bl[2];
        #pragma unroll
        for (int j = 0; j < 2; ++j) {
            int off = (wn + j * 16 + row16) * 64 + quad * 16;
            bh[j] = *(const short8*)((const char*)sBh + off);
            bl[j] = *(const short8*)((const char*)sBl + off);
        }
        #pragma unroll
        for (int i = 0; i < 4; ++i)
            a[i] = *(const short8*)((const char*)sAh + (wm + i * 16 + row16) * 64 + quad * 16);
        #pragma unroll
        for (int i = 0; i < 4; ++i)
            #pragma unroll
            for (int j = 0; j < 2; ++j) {
                acc[i][j] = __builtin_amdgcn_mfma_f32_16x16x32_bf16(a[i], bh[j], acc[i][j], 0, 0, 0);
                acc[i][j] = __builtin_amdgcn_mfma_f32_16x16x32_bf16(a[i], bl[j], acc[i][j], 0, 0, 0);
            }
        #pragma unroll
        for (int i = 0; i < 4; ++i)
            a[i] = *(const short8*)((const char*)sAl + (wm + i * 16 + row16) * 64 + quad * 16);
        #pragma unroll
        for (int i = 0; i < 4; ++i)
            #pragma unroll
            for (int j = 0; j < 2; ++j)
                acc[i][j] = __builtin_amdgcn_mfma_f32_16x16x32_bf16(a[i], bh[j], acc[i][j], 0, 0, 0);
        __syncthreads();
    }
    #pragma unroll
    for (int i = 0; i < 4; ++i)
        #pragma unroll
        for (int j = 0; j < 2; ++j)
            #pragma unroll
            for (int r = 0; r < 4; ++r) {
                int gm = b0 + wm + i * 16 + quad * 4 + r;
                int gn = n0 + wn + j * 16 + row16;
                size_t idx = (size_t)gm * NM + gn;
                float v = acc[i][j][r] - y[idx];
                unsigned short h = f2bf(v);
                Rth[idx] = h;
                Rtl[idx] = f2bf(v - bf2f(h));
            }
}

// ---- fused GEMM2 + exact top-50 select + soft-threshold update ----
// One block = 16 batch rows x full N=1024. V lives in LDS (f32, row-swizzled)
// so registers never hold >8 V elements (rounds 1-6: per-thread f32 arrays
// spilled to scratch -> 0.1-1.2 GB of HBM scratch traffic).
// LDS 80 KB -> 2 blocks/CU:
//   V  [16][1024] f32 @ 0      row 4096B, 16B-chunk addr ^= ((row&7)<<4)
//   Rt h(8K)+l(8K)    @ 65536  dead after GEMM -> hist(8448B)+pref+rk
#define V_OFF 0
#define RH_OFF 65536
#define RL_OFF 73728
#define HIST_OFF 65536
#define HSTRIDE 132                      // words/row: 256 bins packed 2/word + pad
#define HIST_WORDS (16 * HSTRIDE)        // 2112 words = 8448 B
#define PREF_OFF (65536 + 8448)          // u32[16]
#define RK_OFF (65536 + 8512)            // u32[16]
#define LDS_BYTES 81920

template <int FIRST>
__global__ __launch_bounds__(512, 4) void gemm2_update(
        const unsigned short* __restrict__ Rth, const unsigned short* __restrict__ Rtl,
        const unsigned short* __restrict__ Wth, const unsigned short* __restrict__ Wtl,
        const float* __restrict__ y,
        unsigned short* __restrict__ Xh, unsigned short* __restrict__ Xl,
        const float* __restrict__ gamma, const float* __restrict__ theta,
        int it, float* __restrict__ out) {
    extern __shared__ char lds[];
    const int tid = threadIdx.x;
    const int w = tid >> 6;          // wave 0..7
    const int lane = tid & 63;
    const int qd = lane >> 4;        // quad 0..3
    const int r16 = lane & 15;
    const int lrow = lane >> 2;      // row this lane owns in phase B/D (0..15)
    const int lq = lane & 3;         // col-quarter within wave's 128 cols
    const int gb0 = blockIdx.x * BMROW;

    // ---- stage Rt (or -y split when FIRST: X==0 -> Rt=-y) into LDS ----
    {
        const int b = tid >> 5, c = tid & 31;    // row 0..15, 8-elem chunk 0..31
        const unsigned dst = (unsigned)(b * 512 + ((c * 16) ^ ((b & 7) << 4)));
        if (FIRST) {
            float4 v0 = *reinterpret_cast<const float4*>(&y[(size_t)(gb0 + b) * NM + c * 8]);
            float4 v1 = *reinterpret_cast<const float4*>(&y[(size_t)(gb0 + b) * NM + c * 8 + 4]);
            float vv[8] = {v0.x, v0.y, v0.z, v0.w, v1.x, v1.y, v1.z, v1.w};
            short8 hh, ll;
            #pragma unroll
            for (int e = 0; e < 8; ++e) {
                float v = -vv[e];
                unsigned short h = f2bf(v);
                hh[e] = (short)h;
                ll[e] = (short)f2bf(v - bf2f(h));
            }
            *(short8*)(lds + RH_OFF + dst) = hh;
            *(short8*)(lds + RL_OFF + dst) = ll;
        } else {
            size_t g = (size_t)(gb0 + b) * NM + c * 8;
            *(short8*)(lds + RH_OFF + dst) = *(const short8*)(Rth + g);
            *(short8*)(lds + RL_OFF + dst) = *(const short8*)(Rtl + g);
        }
    }
    __syncthreads();   // B1: Rt staged

    // ---- GEMM2: acc2[b,n] = sum_m Rt[b,m]*W[m,n]  (K = 256) ----
    const size_t wn0 = (size_t)(w * 128 + r16) * NM + qd * 8;
    {
        f32x4 acc2[8];
        #pragma unroll
        for (int j = 0; j < 8; ++j) acc2[j] = (f32x4){0.f, 0.f, 0.f, 0.f};

        #pragma unroll 2
        for (int k = 0; k < 8; ++k) {
            const unsigned mo = ((unsigned)(k * 64 + qd * 16)) ^ ((unsigned)((r16 & 7) << 4));
            short8 ah = *(const short8*)(lds + RH_OFF + r16 * 512 + mo);
            short8 al = *(const short8*)(lds + RL_OFF + r16 * 512 + mo);
            #pragma unroll
            for (int jp = 0; jp < 4; ++jp) {
                const int j0 = 2 * jp, j1 = 2 * jp + 1;
                short8 wh0 = *(const short8*)(Wth + wn0 + j0 * 4096 + k * 32);
                short8 wl0 = *(const short8*)(Wtl + wn0 + j0 * 4096 + k * 32);
                short8 wh1 = *(const short8*)(Wth + wn0 + j1 * 4096 + k * 32);
                short8 wl1 = *(const short8*)(Wtl + wn0 + j1 * 4096 + k * 32);
                acc2[j0] = __builtin_amdgcn_mfma_f32_16x16x32_bf16(ah, wh0, acc2[j0], 0, 0, 0);
                acc2[j0] = __builtin_amdgcn_mfma_f32_16x16x32_bf16(ah, wl0, acc2[j0], 0, 0, 0);
                acc2[j0] = __builtin_amdgcn_mfma_f32_16x16x32_bf16(al, wh0, acc2[j0], 0, 0, 0);
                acc2[j1] = __builtin_amdgcn_mfma_f32_16x16x32_bf16(ah, wh1, acc2[j1], 0, 0, 0);
                acc2[j1] = __builtin_amdgcn_mfma_f32_16x16x32_bf16(ah, wl1, acc2[j1], 0, 0, 0);
                acc2[j1] = __builtin_amdgcn_mfma_f32_16x16x32_bf16(al, wh1, acc2[j1], 0, 0, 0);
            }
        }

        // ---- scatter acc2 -> V LDS (f32, row-swizzled); ~2-way conflicts ----
        #pragma unroll
        for (int j = 0; j < 8; ++j) {
            const unsigned colb = (unsigned)((w * 128 + j * 16 + r16) * 4);
            #pragma unroll
            for (int r = 0; r < 4; ++r) {
                const int b = qd * 4 + r;
                *(float*)(lds + V_OFF + b * 4096 + (colb ^ ((unsigned)(b & 7) << 4))) =
                    acc2[j][r];
            }
        }
    }
    __syncthreads();   // B2: V complete; Rt dead -> region reusable for hist

    uint32_t* hist = (uint32_t*)(lds + HIST_OFF);
    uint32_t* prefA = (uint32_t*)(lds + PREF_OFF);
    uint32_t* rkA = (uint32_t*)(lds + RK_OFF);
    #pragma unroll
    for (int i = 0; i < 5; ++i) {
        int idx = tid + i * 512;
        if (idx < HIST_WORDS) hist[idx] = 0u;
    }
    if (tid < 16) { prefA[tid] = 0u; rkA[tid] = TOPK; }
    __syncthreads();   // B3: hist zeroed

    // ---- phase B: v = x_old - gamma*c (V in LDS) + fused select pass 0 ----
    const float gm = gamma[it];
    const float thv = theta[it];
    const unsigned swzr = (unsigned)((lrow & 7) << 4);
    const unsigned vrow = (unsigned)(V_OFF + lrow * 4096);
    const unsigned vbase = (unsigned)((w * 128 + lq * 32) * 4);
    const size_t xg = (size_t)(gb0 + lrow) * NN + w * 128 + lq * 32;
    uint32_t* hrow = hist + lrow * HSTRIDE;
    #pragma unroll
    for (int g = 0; g < 4; ++g) {
        char* p0 = lds + vrow + ((vbase + g * 32) ^ swzr);
        char* p1 = lds + vrow + ((vbase + g * 32 + 16) ^ swzr);
        f32x4 c0 = *(const f32x4*)p0;
        f32x4 c1 = *(const f32x4*)p1;
        float vv[8];
        if (FIRST) {
            #pragma unroll
            for (int e = 0; e < 4; ++e) { vv[e] = -gm * c0[e]; vv[4 + e] = -gm * c1[e]; }
        } else {
            short8 xh = *(const short8*)(Xh + xg + g * 8);
            short8 xl = *(const short8*)(Xl + xg + g * 8);
            #pragma unroll
            for (int e = 0; e < 4; ++e) {
                float xo0 = bf2f((unsigned short)xh[e]) + bf2f((unsigned short)xl[e]);
                float xo1 = bf2f((unsigned short)xh[4 + e]) + bf2f((unsigned short)xl[4 + e]);
                vv[e] = xo0 - gm * c0[e];
                vv[4 + e] = xo1 - gm * c1[e];
            }
        }
        *(f32x4*)p0 = (f32x4){vv[0], vv[1], vv[2], vv[3]};
        *(f32x4*)p1 = (f32x4){vv[4], vv[5], vv[6], vv[7]};
        #pragma unroll
        for (int e = 0; e < 8; ++e) {
            unsigned u = __float_as_uint(vv[e]) & 0x7FFFFFFFu;
            unsigned bin = (u >> 23) & 0xFFu;
            atomicAdd(&hrow[bin >> 1], 1u << ((bin & 1) * 16));
        }
    }
    __syncthreads();   // B4: pass-0 histogram complete

    // ---- exact per-row 50th-largest |v|: radix select (pass0 fused above) ----
    const int srow = w * 4 + qd;   // row scanned by this quad (w<4 only)
    #pragma unroll
    for (int pass = 0; pass < 4; ++pass) {
        const int s = (pass == 0) ? 23 : (pass == 1) ? 15 : (pass == 2) ? 7 : 0;
        if (pass > 0) {
            const int sTop = (pass == 1) ? 23 : (pass == 2) ? 15 : 7;
            const unsigned bmask = (pass == 3) ? 0x7Fu : 0xFFu;
            #pragma unroll
            for (int i = 0; i < 5; ++i) {
                int idx = tid + i * 512;
                if (idx < HIST_WORDS) hist[idx] = 0u;
            }
            __syncthreads();
            const unsigned pref = prefA[lrow];
            #pragma unroll
            for (int g = 0; g < 4; ++g) {
                f32x4 c0 = *(const f32x4*)(lds + vrow + ((vbase + g * 32) ^ swzr));
                f32x4 c1 = *(const f32x4*)(lds + vrow + ((vbase + g * 32 + 16) ^ swzr));
                #pragma unroll
                for (int e = 0; e < 8; ++e) {
                    float vv = (e < 4) ? c0[e & 3] : c1[e & 3];
                    unsigned u = __float_as_uint(vv) & 0x7FFFFFFFu;
                    if ((u >> sTop) == (pref >> sTop)) {
                        unsigned bin = (u >> s) & bmask;
                        atomicAdd(&hrow[bin >> 1], 1u << ((bin & 1) * 16));
                    }
                }
            }
            __syncthreads();
        }
        if (w < 4) {   // one owner quad per row: scan is RMW on prefA/rkA
            unsigned cnt[16];
            unsigned lsum = 0;
            #pragma unroll
            for (int i = 0; i < 8; ++i) {
                unsigned wd = hist[srow * HSTRIDE + r16 * 8 + i];
                cnt[2 * i] = wd & 0xFFFFu;
                cnt[2 * i + 1] = wd >> 16;
                lsum += cnt[2 * i] + cnt[2 * i + 1];
            }
            unsigned S = lsum;
            #pragma unroll
            for (int off = 1; off < 16; off <<= 1) {
                unsigned o = (unsigned)__shfl_down((int)S, off, 16);
                if (r16 + off < 16) S += o;
            }
            const unsigned rk = rkA[srow];
            const unsigned pOld = prefA[srow];
            unsigned run = S - lsum;
            #pragma unroll
            for (int i = 15; i >= 0; --i) {
                unsigned tot = run + cnt[i];
                if (run < rk && tot >= rk) {
                    prefA[srow] = pOld | (((unsigned)(r16 * 16 + i)) << s);
                    rkA[srow] = rk - run;
                }
                run = tot;
            }
        }
        __syncthreads();
    }

    // ---- phase D: soft-threshold + exact top-k passthrough, write X' ----
    const unsigned T = prefA[lrow];
    #pragma unroll
    for (int g = 0; g < 4; ++g) {
        f32x4 c0 = *(const f32x4*)(lds + vrow + ((vbase + g * 32) ^ swzr));
        f32x4 c1 = *(const f32x4*)(lds + vrow + ((vbase + g * 32 + 16) ^ swzr));
        short8 xh, xl;
        if (!FIRST) {
            xh = *(const short8*)(Xh + xg + g * 8);   // L1-hot re-read
            xl = *(const short8*)(Xl + xg + g * 8);
        }
        short8 nh, nl;
        float ov[8];
        #pragma unroll
        for (int e = 0; e < 8; ++e) {
            float xo = FIRST ? 0.0f
                             : bf2f((unsigned short)xh[e]) + bf2f((unsigned short)xl[e]);
            float vv = (e < 4) ? c0[e & 3] : c1[e & 3];
            float th = thv / (10.0f * fabsf(xo) + 1.0f);   // theta*g(|x|), EPS=0.1
            float st = copysignf(fmaxf(fabsf(vv) - th, 0.0f), vv);
            unsigned u = __float_as_uint(vv) & 0x7FFFFFFFu;
            float outv = (u > T) ? vv : st;
            unsigned short h = f2bf(outv);
            nh[e] = (short)h;
            nl[e] = (short)f2bf(outv - bf2f(h));
            ov[e] = outv;
        }
        *(short8*)(Xh + xg + g * 8) = nh;
        *(short8*)(Xl + xg + g * 8) = nl;
        if (it == NITER - 1) {
            float4 o0 = {ov[0], ov[1], ov[2], ov[3]};
            float4 o1 = {ov[4], ov[5], ov[6], ov[7]};
            *reinterpret_cast<float4*>(&out[xg + g * 8]) = o0;
            *reinterpret_cast<float4*>(&out[xg + g * 8 + 4]) = o1;
        }
    }
}

__global__ void tail_kernel(float* __restrict__ out) {
    if (threadIdx.x < 32) out[(size_t)NB * NN + threadIdx.x] = 0.0f;
}

extern "C" void kernel_launch(void* const* d_in, const int* in_sizes, int n_in,
                              void* d_out, int out_size, void* d_ws, size_t ws_size,
                              hipStream_t stream) {
    const float* y     = (const float*)d_in[0];
    const float* phi   = (const float*)d_in[1];
    const float* W     = (const float*)d_in[2];
    const float* gamma = (const float*)d_in[3];
    const float* theta = (const float*)d_in[4];
    float* out = (float*)d_out;

    char* ws = (char*)d_ws;
    size_t off = 0;
    unsigned short* Xh  = (unsigned short*)(ws + off); off += (size_t)NB * NN * 2;  // 32MB
    unsigned short* Xl  = (unsigned short*)(ws + off); off += (size_t)NB * NN * 2;  // 32MB
    unsigned short* Rth = (unsigned short*)(ws + off); off += (size_t)NB * NM * 2;  // 8MB
    unsigned short* Rtl = (unsigned short*)(ws + off); off += (size_t)NB * NM * 2;  // 8MB
    unsigned short* Ph  = (unsigned short*)(ws + off); off += (size_t)NM * NN * 2;  // 512KB
    unsigned short* Pl  = (unsigned short*)(ws + off); off += (size_t)NM * NN * 2;
    unsigned short* Wth = (unsigned short*)(ws + off); off += (size_t)NN * NM * 2;
    unsigned short* Wtl = (unsigned short*)(ws + off); off += (size_t)NN * NM * 2;

    static int attr_done = 0;
    if (!attr_done) {
        (void)hipFuncSetAttribute(reinterpret_cast<const void*>(gemm2_update<0>),
                                  hipFuncAttributeMaxDynamicSharedMemorySize, LDS_BYTES);
        (void)hipFuncSetAttribute(reinterpret_cast<const void*>(gemm2_update<1>),
                                  hipFuncAttributeMaxDynamicSharedMemorySize, LDS_BYTES);
        attr_done = 1;
    }

    split_phi_kernel<<<(NM * NN) / 256, 256, 0, stream>>>(phi, Ph, Pl);
    transpose_split_W<<<dim3(NN / 32, NM / 32), dim3(32, 8), 0, stream>>>(W, Wth, Wtl);

    // it = 0: X == 0 -> Rt = -y staged straight from y; X memsets unnecessary
    gemm2_update<1><<<NBLKS2, 512, LDS_BYTES, stream>>>(Rth, Rtl, Wth, Wtl, y, Xh, Xl,
                                                        gamma, theta, 0, out);
    for (int it = 1; it < NITER; ++it) {
        gemm1_mfma<<<dim3(NB / BM1, NM / BN1), 256, 0, stream>>>(Xh, Xl, Ph, Pl, y, Rth, Rtl);
        gemm2_update<0><<<NBLKS2, 512, LDS_BYTES, stream>>>(Rth, Rtl, Wth, Wtl, y, Xh, Xl,
                                                            gamma, theta, it, out);
    }
    tail_kernel<<<1, 32, 0, stream>>>(out);
}

// Round 9
// 1862.746 us; speedup vs baseline: 1.7035x; 1.7035x over previous
//
#include <hip/hip_runtime.h>
#include <cstdint>

#define NB 16384   // batch
#define NM 256     // M
#define NN 1024    // N
#define NITER 16
#define TOPK 50

typedef __attribute__((ext_vector_type(8))) short short8;   // 8 bf16 = 4 VGPRs
typedef __attribute__((ext_vector_type(4))) float f32x4;

__device__ inline unsigned short f2bf(float x) {            // RNE fp32 -> bf16
    unsigned u = __float_as_uint(x);
    return (unsigned short)((u + 0x7FFFu + ((u >> 16) & 1u)) >> 16);
}
__device__ inline float bf2f(unsigned short h) {
    return __uint_as_float(((unsigned)h) << 16);
}
__device__ inline void gload16(const void* g, void* lds) {  // 16B global -> LDS
    __builtin_amdgcn_global_load_lds(
        (const __attribute__((address_space(1))) unsigned*)g,
        (__attribute__((address_space(3))) unsigned*)lds, 16, 0, 0);
}

// ------------- precompute: element-wise split of phi (NM x NN) -------------
__global__ __launch_bounds__(256) void split_phi_kernel(const float* __restrict__ phi,
                                                        unsigned short* __restrict__ h,
                                                        unsigned short* __restrict__ l) {
    int i = blockIdx.x * 256 + threadIdx.x;
    float v = phi[i];
    unsigned short hh = f2bf(v);
    h[i] = hh;
    l[i] = f2bf(v - bf2f(hh));
}

// -------- precompute: W (NM x NN) -> Wt (NN x NM) transposed + split -------
__global__ __launch_bounds__(256) void transpose_split_W(const float* __restrict__ W,
                                                         unsigned short* __restrict__ th,
                                                         unsigned short* __restrict__ tl) {
    __shared__ float tile[32][33];
    int n0 = blockIdx.x * 32;
    int m0 = blockIdx.y * 32;
    int tx = threadIdx.x;   // 0..31
    int ty = threadIdx.y;   // 0..7
    #pragma unroll
    for (int i = 0; i < 32; i += 8)
        tile[ty + i][tx] = W[(size_t)(m0 + ty + i) * NN + n0 + tx];
    __syncthreads();
    #pragma unroll
    for (int i = 0; i < 32; i += 8) {
        float v = tile[tx][ty + i];
        unsigned short hh = f2bf(v);
        size_t idx = (size_t)(n0 + ty + i) * NM + m0 + tx;
        th[idx] = hh;
        tl[idx] = f2bf(v - bf2f(hh));
    }
}

// ---- it=0 shortcut: X==0 -> Rt = -y (split). Replaces memsets + gemm1. ----
__global__ __launch_bounds__(256) void rt_init_kernel(const float* __restrict__ y,
                                                      unsigned short* __restrict__ Rth,
                                                      unsigned short* __restrict__ Rtl) {
    size_t i = ((size_t)blockIdx.x * 256 + threadIdx.x) * 4;
    float4 v4 = *reinterpret_cast<const float4*>(&y[i]);
    float vv[4] = {v4.x, v4.y, v4.z, v4.w};
    ushort4 h4, l4;
    unsigned short* hp = reinterpret_cast<unsigned short*>(&h4);
    unsigned short* lp = reinterpret_cast<unsigned short*>(&l4);
    #pragma unroll
    for (int e = 0; e < 4; ++e) {
        float v = -vv[e];
        unsigned short h = f2bf(v);
        hp[e] = h;
        lp[e] = f2bf(v - bf2f(h));
    }
    *reinterpret_cast<ushort4*>(&Rth[i]) = h4;
    *reinterpret_cast<ushort4*>(&Rtl[i]) = l4;
}

// ---- GEMM1 (round-0 verbatim, proven): Rt(B x NM) = X(B x NN) @ phiT - y ----
#define BM1 128
#define BN1 64
#define BK  32
__global__ __launch_bounds__(256) void gemm1_mfma(const unsigned short* __restrict__ Xh,
                                                  const unsigned short* __restrict__ Xl,
                                                  const unsigned short* __restrict__ Ph,
                                                  const unsigned short* __restrict__ Pl,
                                                  const float* __restrict__ y,
                                                  unsigned short* __restrict__ Rth,
                                                  unsigned short* __restrict__ Rtl) {
    __shared__ unsigned short sAh[BM1 * BK];  // 8KB, row stride 32 elem = 64B
    __shared__ unsigned short sAl[BM1 * BK];
    __shared__ unsigned short sBh[BN1 * BK];  // 4KB
    __shared__ unsigned short sBl[BN1 * BK];

    const int tid = threadIdx.x, wave = tid >> 6, lane = tid & 63;
    const int b0 = blockIdx.x * BM1, n0 = blockIdx.y * BN1;
    const int wm = (wave & 1) * 64, wn = (wave >> 1) * 32;
    const int row16 = lane & 15, quad = lane >> 4;

    f32x4 acc[4][2];
    #pragma unroll
    for (int i = 0; i < 4; i++)
        #pragma unroll
        for (int j = 0; j < 2; j++) acc[i][j] = (f32x4){0.f, 0.f, 0.f, 0.f};

    for (int k0 = 0; k0 < NN; k0 += BK) {
        #pragma unroll
        for (int c = 0; c < 2; ++c) {          // A tiles: 8 chunks of 1KB
            int o = (wave * 2 + c) * 1024 + lane * 16;   // byte offset in tile
            int row = o >> 6, colb = o & 63;
            size_t g = (size_t)(b0 + row) * NN + k0 + (colb >> 1);
            gload16(&Xh[g], (char*)sAh + o);
            gload16(&Xl[g], (char*)sAl + o);
        }
        {                                       // B tiles: 4 chunks of 1KB
            int o = wave * 1024 + lane * 16;
            int nrow = o >> 6, colb = o & 63;
            size_t g = (size_t)(n0 + nrow) * NN + k0 + (colb >> 1);
            gload16(&Ph[g], (char*)sBh + o);
            gload16(&Pl[g], (char*)sBl + o);
        }
        __syncthreads();
        short8 a[4], bh[2], bl[2];
        #pragma unroll
        for (int j = 0; j < 2; ++j) {
            int off = (wn + j * 16 + row16) * 64 + quad * 16;
            bh[j] = *(const short8*)((const char*)sBh + off);
            bl[j] = *(const short8*)((const char*)sBl + off);
        }
        #pragma unroll
        for (int i = 0; i < 4; ++i)
            a[i] = *(const short8*)((const char*)sAh + (wm + i * 16 + row16) * 64 + quad * 16);
        #pragma unroll
        for (int i = 0; i < 4; ++i)
            #pragma unroll
            for (int j = 0; j < 2; ++j) {
                acc[i][j] = __builtin_amdgcn_mfma_f32_16x16x32_bf16(a[i], bh[j], acc[i][j], 0, 0, 0);
                acc[i][j] = __builtin_amdgcn_mfma_f32_16x16x32_bf16(a[i], bl[j], acc[i][j], 0, 0, 0);
            }
        #pragma unroll
        for (int i = 0; i < 4; ++i)
            a[i] = *(const short8*)((const char*)sAl + (wm + i * 16 + row16) * 64 + quad * 16);
        #pragma unroll
        for (int i = 0; i < 4; ++i)
            #pragma unroll
            for (int j = 0; j < 2; ++j)
                acc[i][j] = __builtin_amdgcn_mfma_f32_16x16x32_bf16(a[i], bh[j], acc[i][j], 0, 0, 0);
        __syncthreads();
    }
    #pragma unroll
    for (int i = 0; i < 4; ++i)
        #pragma unroll
        for (int j = 0; j < 2; ++j)
            #pragma unroll
            for (int r = 0; r < 4; ++r) {
                int gm = b0 + wm + i * 16 + quad * 4 + r;
                int gn = n0 + wn + j * 16 + row16;
                size_t idx = (size_t)gm * NM + gn;
                float v = acc[i][j][r] - y[idx];
                unsigned short h = f2bf(v);
                Rth[idx] = h;
                Rtl[idx] = f2bf(v - bf2f(h));
            }
}

// ---- GEMM2 lean: C(B x NN) = Rt(B x NM) @ W(NM x NN), raw f32 out ----
// (x - gamma*c moved to update_kernel, which reads X anyway: saves the X
//  read stream here; identical arithmetic/bits overall.)
#define BM2 128
#define BN2 128
__global__ __launch_bounds__(256) void gemm2_mfma(const unsigned short* __restrict__ Rth,
                                                  const unsigned short* __restrict__ Rtl,
                                                  const unsigned short* __restrict__ Wth,
                                                  const unsigned short* __restrict__ Wtl,
                                                  float* __restrict__ C) {
    __shared__ unsigned short sAh[BM2 * BK];  // 8KB each
    __shared__ unsigned short sAl[BM2 * BK];
    __shared__ unsigned short sBh[BN2 * BK];
    __shared__ unsigned short sBl[BN2 * BK];

    const int tid = threadIdx.x, wave = tid >> 6, lane = tid & 63;
    const int b0 = blockIdx.x * BM2, n0 = blockIdx.y * BN2;
    const int wm = (wave & 1) * 64, wn = (wave >> 1) * 64;
    const int row16 = lane & 15, quad = lane >> 4;

    f32x4 acc[4][4];
    #pragma unroll
    for (int i = 0; i < 4; i++)
        #pragma unroll
        for (int j = 0; j < 4; j++) acc[i][j] = (f32x4){0.f, 0.f, 0.f, 0.f};

    for (int k0 = 0; k0 < NM; k0 += BK) {
        #pragma unroll
        for (int c = 0; c < 2; ++c) {
            int o = (wave * 2 + c) * 1024 + lane * 16;
            int row = o >> 6, colb = o & 63;
            size_t gA = (size_t)(b0 + row) * NM + k0 + (colb >> 1);
            gload16(&Rth[gA], (char*)sAh + o);
            gload16(&Rtl[gA], (char*)sAl + o);
            size_t gB = (size_t)(n0 + row) * NM + k0 + (colb >> 1);
            gload16(&Wth[gB], (char*)sBh + o);
            gload16(&Wtl[gB], (char*)sBl + o);
        }
        __syncthreads();
        short8 a[4], bh[4], bl[4];
        #pragma unroll
        for (int j = 0; j < 4; ++j) {
            int off = (wn + j * 16 + row16) * 64 + quad * 16;
            bh[j] = *(const short8*)((const char*)sBh + off);
            bl[j] = *(const short8*)((const char*)sBl + off);
        }
        #pragma unroll
        for (int i = 0; i < 4; ++i)
            a[i] = *(const short8*)((const char*)sAh + (wm + i * 16 + row16) * 64 + quad * 16);
        #pragma unroll
        for (int i = 0; i < 4; ++i)
            #pragma unroll
            for (int j = 0; j < 4; ++j) {
                acc[i][j] = __builtin_amdgcn_mfma_f32_16x16x32_bf16(a[i], bh[j], acc[i][j], 0, 0, 0);
                acc[i][j] = __builtin_amdgcn_mfma_f32_16x16x32_bf16(a[i], bl[j], acc[i][j], 0, 0, 0);
            }
        #pragma unroll
        for (int i = 0; i < 4; ++i)
            a[i] = *(const short8*)((const char*)sAl + (wm + i * 16 + row16) * 64 + quad * 16);
        #pragma unroll
        for (int i = 0; i < 4; ++i)
            #pragma unroll
            for (int j = 0; j < 4; ++j)
                acc[i][j] = __builtin_amdgcn_mfma_f32_16x16x32_bf16(a[i], bh[j], acc[i][j], 0, 0, 0);
        __syncthreads();
    }
    #pragma unroll
    for (int i = 0; i < 4; ++i)
        #pragma unroll
        for (int j = 0; j < 4; ++j)
            #pragma unroll
            for (int r = 0; r < 4; ++r) {
                int gmr = b0 + wm + i * 16 + quad * 4 + r;
                int gn = n0 + wn + j * 16 + row16;
                C[(size_t)gmr * NN + gn] = acc[i][j][r];
            }
}

// -------- update: v = x - gamma*c, exact top-50 |v| via 2048-bin select ----
// (round-0 proven select; v computed inline from C + X.)
template <int FIRST>
__global__ __launch_bounds__(256) void update_kernel(const float* __restrict__ C,
                                                     unsigned short* __restrict__ Xh,
                                                     unsigned short* __restrict__ Xl,
                                                     const float* __restrict__ gamma,
                                                     const float* __restrict__ theta,
                                                     int it,
                                                     float* __restrict__ out) {
    __shared__ unsigned hist[2048];    // 8KB
    __shared__ unsigned wtot[4];
    __shared__ unsigned s_bin;
    __shared__ unsigned s_r2;
    __shared__ unsigned s_cnt;
    __shared__ unsigned s_T;
    __shared__ unsigned s_low[1024];   // 4KB worst case

    const int b = blockIdx.x, tid = threadIdx.x;
    const int lane = tid & 63, wave = tid >> 6;
    const size_t base = (size_t)b * NN + tid * 4;
    const float gm = gamma[it];

    float4 cc = *reinterpret_cast<const float4*>(&C[base]);
    float c4[4] = {cc.x, cc.y, cc.z, cc.w};

    ushort4 xh4, xl4;
    float xo[4];
    if (FIRST) {
        xo[0] = xo[1] = xo[2] = xo[3] = 0.0f;
    } else {
        xh4 = *reinterpret_cast<const ushort4*>(&Xh[base]);
        xl4 = *reinterpret_cast<const ushort4*>(&Xl[base]);
        const unsigned short* xhp = reinterpret_cast<const unsigned short*>(&xh4);
        const unsigned short* xlp = reinterpret_cast<const unsigned short*>(&xl4);
        #pragma unroll
        for (int j = 0; j < 4; j++) xo[j] = bf2f(xhp[j]) + bf2f(xlp[j]);
    }

    float v[4];
    unsigned u[4];
    #pragma unroll
    for (int j = 0; j < 4; j++) {
        v[j] = xo[j] - gm * c4[j];
        u[j] = __float_as_uint(fabsf(v[j]));
    }

    // clear
    uint4 z4 = {0u, 0u, 0u, 0u};
    reinterpret_cast<uint4*>(hist)[tid] = z4;
    reinterpret_cast<uint4*>(hist)[tid + 256] = z4;
    if (tid == 0) s_cnt = 0;
    __syncthreads();

    #pragma unroll
    for (int j = 0; j < 4; j++) atomicAdd(&hist[u[j] >> 20], 1u);
    __syncthreads();

    // thread t owns bins [t*8, t*8+8)
    unsigned loc[8];
    uint4 h0 = reinterpret_cast<const uint4*>(hist)[tid * 2];
    uint4 h1 = reinterpret_cast<const uint4*>(hist)[tid * 2 + 1];
    loc[0] = h0.x; loc[1] = h0.y; loc[2] = h0.z; loc[3] = h0.w;
    loc[4] = h1.x; loc[5] = h1.y; loc[6] = h1.z; loc[7] = h1.w;
    unsigned lsum = 0;
    #pragma unroll
    for (int i = 0; i < 8; i++) lsum += loc[i];

    // wave-level inclusive suffix scan of lsum (no LDS, no barriers)
    unsigned s = lsum;
    #pragma unroll
    for (int off = 1; off < 64; off <<= 1) {
        unsigned o = __shfl_down(s, off, 64);
        if (lane + off < 64) s += o;
    }
    if (lane == 0) wtot[wave] = s;   // wave total
    __syncthreads();
    unsigned after_wave = 0;
    #pragma unroll
    for (int w = 0; w < 4; ++w)
        if (w > wave) after_wave += wtot[w];
    unsigned S_incl = s + after_wave;      // suffix incl. this thread's bins
    unsigned run = S_incl - lsum;          // suffix of all higher bins

    const unsigned r = TOPK;
    #pragma unroll
    for (int i = 7; i >= 0; --i) {         // high bin = larger value
        unsigned sufThis = run + loc[i];
        if (sufThis >= r && run < r) { s_bin = tid * 8 + i; s_r2 = r - run; }
        run = sufThis;
    }
    __syncthreads();
    const unsigned bin = s_bin, r2 = s_r2;

    // collect low-20-bit remainders of prefix-matching elements
    #pragma unroll
    for (int j = 0; j < 4; j++) {
        if ((u[j] >> 20) == bin) {
            unsigned p = atomicAdd(&s_cnt, 1u);
            s_low[p] = u[j] & 0xFFFFFu;
        }
    }
    __syncthreads();
    const unsigned c = s_cnt;
    for (unsigned p = tid; p < c; p += 256) {
        unsigned x = s_low[p];
        unsigned cg = 0, ce = 0;
        for (unsigned q = 0; q < c; ++q) {
            unsigned yq = s_low[q];
            cg += (yq > x);
            ce += (yq == x);
        }
        if (cg < r2 && cg + ce >= r2) s_T = (bin << 20) | x;
    }
    __syncthreads();
    const unsigned T = s_T;   // exact bit pattern of 50th-largest |v|

    // epilogue: soft-threshold + exact top-k passthrough, split-write X
    float thv = theta[it];
    ushort4 nh4, nl4;
    unsigned short* nhp = reinterpret_cast<unsigned short*>(&nh4);
    unsigned short* nlp = reinterpret_cast<unsigned short*>(&nl4);
    float ov[4];
    #pragma unroll
    for (int j = 0; j < 4; j++) {
        float th = thv / (10.0f * fabsf(xo[j]) + 1.0f);   // theta * g(|x|), EPS=0.1
        float a = fabsf(v[j]);
        float st = copysignf(fmaxf(a - th, 0.0f), v[j]);
        float outv = (u[j] > T) ? v[j] : st;
        unsigned short h = f2bf(outv);
        nhp[j] = h;
        nlp[j] = f2bf(outv - bf2f(h));
        ov[j] = outv;
    }
    *reinterpret_cast<ushort4*>(&Xh[base]) = nh4;
    *reinterpret_cast<ushort4*>(&Xl[base]) = nl4;
    if (it == NITER - 1)
        *reinterpret_cast<float4*>(&out[base]) = *reinterpret_cast<float4*>(ov);
}

__global__ void tail_kernel(float* __restrict__ out) {
    if (threadIdx.x < 32) out[(size_t)NB * NN + threadIdx.x] = 0.0f;
}

extern "C" void kernel_launch(void* const* d_in, const int* in_sizes, int n_in,
                              void* d_out, int out_size, void* d_ws, size_t ws_size,
                              hipStream_t stream) {
    const float* y     = (const float*)d_in[0];
    const float* phi   = (const float*)d_in[1];
    const float* W     = (const float*)d_in[2];
    const float* gamma = (const float*)d_in[3];
    const float* theta = (const float*)d_in[4];
    float* out = (float*)d_out;

    char* ws = (char*)d_ws;
    size_t off = 0;
    unsigned short* Xh  = (unsigned short*)(ws + off); off += (size_t)NB * NN * 2;  // 32MB
    unsigned short* Xl  = (unsigned short*)(ws + off); off += (size_t)NB * NN * 2;  // 32MB
    unsigned short* Rth = (unsigned short*)(ws + off); off += (size_t)NB * NM * 2;  // 8MB
    unsigned short* Rtl = (unsigned short*)(ws + off); off += (size_t)NB * NM * 2;  // 8MB
    unsigned short* Ph  = (unsigned short*)(ws + off); off += (size_t)NM * NN * 2;  // 512KB
    unsigned short* Pl  = (unsigned short*)(ws + off); off += (size_t)NM * NN * 2;
    unsigned short* Wth = (unsigned short*)(ws + off); off += (size_t)NN * NM * 2;
    unsigned short* Wtl = (unsigned short*)(ws + off); off += (size_t)NN * NM * 2;
    float* C = out;   // C scratch aliases output (fully rewritten each iter;
                      // update reads C[i] then writes out[i] in-thread)

    split_phi_kernel<<<(NM * NN) / 256, 256, 0, stream>>>(phi, Ph, Pl);
    transpose_split_W<<<dim3(NN / 32, NM / 32), dim3(32, 8), 0, stream>>>(W, Wth, Wtl);

    // it = 0: X == 0 -> Rt = -y directly; no memsets, no gemm1 on zeros
    rt_init_kernel<<<(NB * NM) / (256 * 4), 256, 0, stream>>>(y, Rth, Rtl);
    gemm2_mfma<<<dim3(NB / BM2, NN / BN2), 256, 0, stream>>>(Rth, Rtl, Wth, Wtl, C);
    update_kernel<1><<<NB, 256, 0, stream>>>(C, Xh, Xl, gamma, theta, 0, out);

    for (int it = 1; it < NITER; ++it) {
        gemm1_mfma<<<dim3(NB / BM1, NM / BN1), 256, 0, stream>>>(Xh, Xl, Ph, Pl, y, Rth, Rtl);
        gemm2_mfma<<<dim3(NB / BM2, NN / BN2), 256, 0, stream>>>(Rth, Rtl, Wth, Wtl, C);
        update_kernel<0><<<NB, 256, 0, stream>>>(C, Xh, Xl, gamma, theta, it, out);
    }
    tail_kernel<<<1, 32, 0, stream>>>(out);
}